// Round 6
// baseline (296.181 us; speedup 1.0000x reference)
//
#include <hip/hip_runtime.h>

#define N_DENSE 13
#define N_FIELDS 26
#define PER_FIELD 100000
#define FEATURE_NUM (N_FIELDS * PER_FIELD + N_DENSE)  // 2,600,013
#define K_DIM 16
#define BATCH 4096

// ---------------- Phase 1: transpose V[16][F] -> Vt[F][16] in d_ws ----------
// Coalesced reads (wave reads 256 B contiguous per k), 64 B/thread writes.
__global__ __launch_bounds__(256) void transpose_v_kernel(
    const float* __restrict__ V,   // [16, FEATURE_NUM]
    float*       __restrict__ Vt)  // [FEATURE_NUM, 16]
{
    const int stride = gridDim.x * blockDim.x;
    for (int f = blockIdx.x * blockDim.x + threadIdx.x; f < FEATURE_NUM; f += stride) {
        float vals[K_DIM];
        #pragma unroll
        for (int k = 0; k < K_DIM; ++k) {
            vals[k] = V[(size_t)k * FEATURE_NUM + f];
        }
        float4* dst = (float4*)(Vt + (size_t)f * K_DIM);
        #pragma unroll
        for (int j = 0; j < 4; ++j) {
            dst[j] = make_float4(vals[4 * j], vals[4 * j + 1], vals[4 * j + 2], vals[4 * j + 3]);
        }
    }
}

// ---------------- Phase 2: FM from transposed Vt ----------------------------
// 2 waves per row, 2 rows per 256-thread block.
// lane-in-wave: fL = lane>>2 (0..15), q = lane&3 (which float4 of the 16).
// f = halfw*16 + fL in 0..31 (sparse valid f<26; dense d=f<13 on halfw==0).
__global__ __launch_bounds__(256) void fm_gather_kernel(
    const float* __restrict__ dense,   // [B, 13]
    const int*   __restrict__ sparse,  // [B, 26]
    const float* __restrict__ w0,      // [1]
    const float* __restrict__ w,       // [FEATURE_NUM]
    const float* __restrict__ Vt,      // [FEATURE_NUM, 16] (d_ws)
    float*       __restrict__ out)     // [B]
{
    const int wave  = threadIdx.x >> 6;     // 0..3
    const int lane  = threadIdx.x & 63;
    const int row   = wave >> 1;            // 0..1
    const int halfw = wave & 1;             // 0..1
    const int b = blockIdx.x * 2 + row;

    const int fL = lane >> 2;               // 0..15
    const int q  = lane & 3;                // 0..3
    const int f  = halfw * 16 + fL;         // 0..31

    const float4* Vt4 = (const float4*)Vt;

    float e[4]  = {0.f, 0.f, 0.f, 0.f};
    float sq[4] = {0.f, 0.f, 0.f, 0.f};
    float lin = 0.f;

    // ---- sparse field f (if valid): one 64B latent row, this lane takes quarter q
    if (f < N_FIELDS) {
        const int g = N_DENSE + f * PER_FIELD + sparse[b * N_FIELDS + f];
        float4 v = Vt4[(size_t)g * 4 + q];
        e[0] += v.x; e[1] += v.y; e[2] += v.z; e[3] += v.w;
        sq[0] += v.x * v.x; sq[1] += v.y * v.y; sq[2] += v.z * v.z; sq[3] += v.w * v.w;
        if (q == 0) lin += w[g];
    }

    // ---- dense dim d = f (only halfw==0 covers 0..12); rows 0..12 of Vt ----
    if (halfw == 0 && f < N_DENSE) {
        const float x = dense[b * N_DENSE + f];
        float4 v = Vt4[(size_t)f * 4 + q];
        e[0] += x * v.x; e[1] += x * v.y; e[2] += x * v.z; e[3] += x * v.w;
        const float x2 = x * x;
        sq[0] += x2 * v.x * v.x; sq[1] += x2 * v.y * v.y;
        sq[2] += x2 * v.z * v.z; sq[3] += x2 * v.w * v.w;
        if (q == 0) lin += x * w[f];
    }

    // ---- reduce over the 16 fL groups within the wave (masks preserve q) ----
    #pragma unroll
    for (int m = 4; m <= 32; m <<= 1) {
        #pragma unroll
        for (int c = 0; c < 4; ++c) {
            e[c]  += __shfl_xor(e[c], m, 64);
            sq[c] += __shfl_xor(sq[c], m, 64);
        }
        lin += __shfl_xor(lin, m, 64);
    }

    // ---- cross-wave (pair) combine through LDS ----
    __shared__ float sE[2][2][4][4];
    __shared__ float sS[2][2][4][4];
    __shared__ float sL[2][2];
    if (lane < 4) {
        #pragma unroll
        for (int c = 0; c < 4; ++c) {
            sE[row][halfw][q][c] = e[c];
            sS[row][halfw][q][c] = sq[c];
        }
    }
    if (lane == 0) sL[row][halfw] = lin;
    __syncthreads();

    if (halfw == 0 && lane < 4) {
        float t = 0.f;
        #pragma unroll
        for (int c = 0; c < 4; ++c) {
            float eT = sE[row][0][q][c] + sE[row][1][q][c];
            float sT = sS[row][0][q][c] + sS[row][1][q][c];
            t += eT * eT - sT;
        }
        t += __shfl_xor(t, 1, 64);
        t += __shfl_xor(t, 2, 64);
        if (lane == 0) {
            out[b] = w0[0] + sL[row][0] + sL[row][1] + 0.5f * t;
        }
    }
}

extern "C" void kernel_launch(void* const* d_in, const int* in_sizes, int n_in,
                              void* d_out, int out_size, void* d_ws, size_t ws_size,
                              hipStream_t stream) {
    const float* dense  = (const float*)d_in[0];
    const int*   sparse = (const int*)d_in[1];
    const float* w0     = (const float*)d_in[2];
    const float* w      = (const float*)d_in[3];
    const float* V      = (const float*)d_in[4];
    float* out = (float*)d_out;
    float* Vt  = (float*)d_ws;  // needs FEATURE_NUM*16*4 = 166.4 MB, ws is ~650 MB

    transpose_v_kernel<<<2048, 256, 0, stream>>>(V, Vt);
    fm_gather_kernel<<<BATCH / 2, 256, 0, stream>>>(dense, sparse, w0, w, Vt, out);
}

// Round 7
// 263.938 us; speedup vs baseline: 1.1222x; 1.1222x over previous
//
#include <hip/hip_runtime.h>

#define N_DENSE 13
#define N_FIELDS 26
#define PER_FIELD 100000
#define FEATURE_NUM (N_FIELDS * PER_FIELD + N_DENSE)  // 2,600,013
#define K_DIM 16
#define BATCH 4096

// d_ws layout (float-element offsets):
//   ws_v   [26][16][4096]  gathered V values per (field, k, row)
//   ws_lin [26][4096]      gathered w values per (field, row)
//   sT     [26][4096]      transposed sparse indices (int)
#define WS_V_OFF   0
#define WS_L_OFF   (N_FIELDS * K_DIM * BATCH)              // 1,703,936
#define WS_S_OFF   (WS_L_OFF + N_FIELDS * BATCH)           // 1,810,432

// ---- Kernel 1: transpose sparse [B][26] -> sT [26][B] (coalesced writes) ----
__global__ __launch_bounds__(256) void transpose_sparse_kernel(
    const int* __restrict__ sparse, int* __restrict__ sT)
{
    const int b = blockIdx.x * blockDim.x + threadIdx.x;  // 0..4095
    if (b >= BATCH) return;
    #pragma unroll
    for (int f = 0; f < N_FIELDS; ++f) {
        sT[f * BATCH + b] = sparse[b * N_FIELDS + f];
    }
}

// ---- Kernel 2: locality-blocked gather. One block per (f, k). -------------
// All 4096 gathers of a block land in one 400KB window of V row k
// -> DRAM row-buffer locality + L2 dedup of repeated lines.
__global__ __launch_bounds__(512) void gather_kernel(
    const int*   __restrict__ sT,     // [26][4096]
    const float* __restrict__ w,      // [FEATURE_NUM]
    const float* __restrict__ V,      // [16][FEATURE_NUM]
    float*       __restrict__ ws_v,   // [26][16][4096]
    float*       __restrict__ ws_lin) // [26][4096]
{
    const int f = blockIdx.x >> 4;        // 0..25
    const int k = blockIdx.x & 15;        // 0..15
    const int tid = threadIdx.x;          // 0..511

    const int base = N_DENSE + f * PER_FIELD;
    const float* __restrict__ Vrow = V + (size_t)k * FEATURE_NUM + base;
    const int* __restrict__ sTf = sT + f * BATCH;

    int   idx[8];
    float v[8];
    #pragma unroll
    for (int r = 0; r < 8; ++r) idx[r] = sTf[r * 512 + tid];
    #pragma unroll
    for (int r = 0; r < 8; ++r) v[r] = Vrow[idx[r]];
    float* __restrict__ dst = ws_v + ((size_t)f * K_DIM + k) * BATCH;
    #pragma unroll
    for (int r = 0; r < 8; ++r) dst[r * 512 + tid] = v[r];

    if (k == 0) {
        const float* __restrict__ wf = w + base;
        float wl[8];
        #pragma unroll
        for (int r = 0; r < 8; ++r) wl[r] = wf[idx[r]];
        float* __restrict__ dl = ws_lin + (size_t)f * BATCH;
        #pragma unroll
        for (int r = 0; r < 8; ++r) dl[r * 512 + tid] = wl[r];
    }
}

// ---- Kernel 3: reduce. thread = (k, b-local); 16 rows x 16 k per block. ----
__global__ __launch_bounds__(256) void reduce_kernel(
    const float* __restrict__ dense,   // [B][13]
    const float* __restrict__ w0,      // [1]
    const float* __restrict__ w,       // [FEATURE_NUM]
    const float* __restrict__ V,       // [16][FEATURE_NUM]
    const float* __restrict__ ws_v,    // [26][16][4096]
    const float* __restrict__ ws_lin,  // [26][4096]
    float*       __restrict__ out)     // [B]
{
    const int bl = threadIdx.x & 15;       // row within block chunk
    const int k  = threadIdx.x >> 4;       // 0..15
    const int b  = blockIdx.x * 16 + bl;

    float e = 0.f, sq = 0.f;
    #pragma unroll
    for (int f = 0; f < N_FIELDS; ++f) {
        float v = ws_v[((size_t)f * K_DIM + k) * BATCH + b];
        e  += v;
        sq += v * v;
    }
    #pragma unroll
    for (int d = 0; d < N_DENSE; ++d) {
        float x  = dense[b * N_DENSE + d];
        float vv = V[(size_t)k * FEATURE_NUM + d];
        e  += x * vv;
        sq += (x * x) * (vv * vv);
    }
    float t = e * e - sq;

    __shared__ float sTile[K_DIM][17];
    sTile[k][bl] = t;
    __syncthreads();

    if (k == 0) {
        float tt = 0.f;
        #pragma unroll
        for (int kk = 0; kk < K_DIM; ++kk) tt += sTile[kk][bl];
        float lin = 0.f;
        #pragma unroll
        for (int f = 0; f < N_FIELDS; ++f) lin += ws_lin[f * BATCH + b];
        #pragma unroll
        for (int d = 0; d < N_DENSE; ++d) lin += dense[b * N_DENSE + d] * w[d];
        out[b] = w0[0] + lin + 0.5f * tt;
    }
}

extern "C" void kernel_launch(void* const* d_in, const int* in_sizes, int n_in,
                              void* d_out, int out_size, void* d_ws, size_t ws_size,
                              hipStream_t stream) {
    const float* dense  = (const float*)d_in[0];
    const int*   sparse = (const int*)d_in[1];
    const float* w0     = (const float*)d_in[2];
    const float* w      = (const float*)d_in[3];
    const float* V      = (const float*)d_in[4];
    float* out = (float*)d_out;

    float* wsf    = (float*)d_ws;
    float* ws_v   = wsf + WS_V_OFF;
    float* ws_lin = wsf + WS_L_OFF;
    int*   sT     = (int*)(wsf + WS_S_OFF);

    transpose_sparse_kernel<<<BATCH / 256, 256, 0, stream>>>(sparse, sT);
    gather_kernel<<<N_FIELDS * K_DIM, 512, 0, stream>>>(sT, w, V, ws_v, ws_lin);
    reduce_kernel<<<BATCH / 16, 256, 0, stream>>>(dense, w0, w, V, ws_v, ws_lin, out);
}